// Round 3
// baseline (776.339 us; speedup 1.0000x reference)
//
#include <hip/hip_runtime.h>

// SimpleRNN: B=16384, T=2048, I=1, H=20, O=1, fp32.
// 4 threads per batch element, each owns 5 hidden rows (h distributed across
// a quad, exchanged per step via DPP quad_perm broadcast - VALU pipe).
// 65536 threads = 1024 waves = 1 wave/SIMD chip-wide.
//
// Round-3 change: __launch_bounds__(256,1) does NOT cap the compiler's
// occupancy target - it still budgeted 84 VGPRs (a ~6-wave target) and
// spilled the 100 W_hh weights every step (round 1+2: VGPR_Count=84).
// amdgpu_waves_per_eu(1,1) gives the allocator the full 1-wave budget
// (256 addressable VGPRs + AGPRs) so all weights stay resident.

#define RNN_T 2048
#define RNN_H 20
#define RNN_B 16384

template <int CTRL>
__device__ __forceinline__ float qb(float v) {
    // v_mov_b32_dpp quad_perm broadcast: CTRL = q * 0x55 broadcasts quad-lane q.
    return __builtin_bit_cast(
        float, __builtin_amdgcn_mov_dpp(__builtin_bit_cast(int, v), CTRL, 0xF, 0xF, true));
}

__device__ __forceinline__ float tanh_fast(float a) {
    // tanh(a) = 1 - 2/(exp2(2*log2e*a)+1); exact limits at +/-inf.
    float e = __builtin_amdgcn_exp2f(a * 2.885390081777927f);
    float r = __builtin_amdgcn_rcpf(e + 1.0f);
    return fmaf(-2.0f, r, 1.0f);
}

// Apply M(R,C) for C = 0..19
#define COLS(M, R)                                                              \
    M(R, 0) M(R, 1) M(R, 2) M(R, 3) M(R, 4) M(R, 5) M(R, 6) M(R, 7) M(R, 8)    \
    M(R, 9) M(R, 10) M(R, 11) M(R, 12) M(R, 13) M(R, 14) M(R, 15) M(R, 16)     \
    M(R, 17) M(R, 18) M(R, 19)

#define DECLW(R, C) float w##R##_##C = Wp[(R) * RNN_H + (C)];
#define ACC(R, C) acc##R = fmaf(w##R##_##C, ha##C, acc##R);

// One RNN step. Reads h0..h4 (previous step, all quad lanes in lockstep),
// writes h0..h4. ha{q*5+i} = quad-lane q's h{i}.
#define STEP(XS)                                                                 \
    do {                                                                         \
        float ha0 = qb<0x00>(h0), ha1 = qb<0x00>(h1), ha2 = qb<0x00>(h2),        \
              ha3 = qb<0x00>(h3), ha4 = qb<0x00>(h4);                            \
        float ha5 = qb<0x55>(h0), ha6 = qb<0x55>(h1), ha7 = qb<0x55>(h2),        \
              ha8 = qb<0x55>(h3), ha9 = qb<0x55>(h4);                            \
        float ha10 = qb<0xAA>(h0), ha11 = qb<0xAA>(h1), ha12 = qb<0xAA>(h2),     \
              ha13 = qb<0xAA>(h3), ha14 = qb<0xAA>(h4);                          \
        float ha15 = qb<0xFF>(h0), ha16 = qb<0xFF>(h1), ha17 = qb<0xFF>(h2),     \
              ha18 = qb<0xFF>(h3), ha19 = qb<0xFF>(h4);                          \
        float acc0 = fmaf(XS, wih0, bias0);                                      \
        float acc1 = fmaf(XS, wih1, bias1);                                      \
        float acc2 = fmaf(XS, wih2, bias2);                                      \
        float acc3 = fmaf(XS, wih3, bias3);                                      \
        float acc4 = fmaf(XS, wih4, bias4);                                      \
        COLS(ACC, 0) COLS(ACC, 1) COLS(ACC, 2) COLS(ACC, 3) COLS(ACC, 4)         \
        h0 = tanh_fast(acc0);                                                    \
        h1 = tanh_fast(acc1);                                                    \
        h2 = tanh_fast(acc2);                                                    \
        h3 = tanh_fast(acc3);                                                    \
        h4 = tanh_fast(acc4);                                                    \
    } while (0)

__attribute__((amdgpu_flat_work_group_size(256, 256), amdgpu_waves_per_eu(1, 1)))
__global__ void rnn_fwd(const float* __restrict__ x,
                        const float* __restrict__ W_ih,
                        const float* __restrict__ W_hh,
                        const float* __restrict__ b_ih,
                        const float* __restrict__ b_hh,
                        const float* __restrict__ W_fc,
                        const float* __restrict__ b_fc,
                        float* __restrict__ out) {
    const int gid  = blockIdx.x * blockDim.x + threadIdx.x;
    const int b    = gid >> 2;   // batch element
    const int part = gid & 3;    // quad-lane == which 5 rows this thread owns

    const float* Wp = W_hh + part * 5 * RNN_H;
    COLS(DECLW, 0) COLS(DECLW, 1) COLS(DECLW, 2) COLS(DECLW, 3) COLS(DECLW, 4)

    const int o0 = part * 5;
    float wih0 = W_ih[o0 + 0], wih1 = W_ih[o0 + 1], wih2 = W_ih[o0 + 2],
          wih3 = W_ih[o0 + 3], wih4 = W_ih[o0 + 4];
    float bias0 = b_ih[o0 + 0] + b_hh[o0 + 0], bias1 = b_ih[o0 + 1] + b_hh[o0 + 1],
          bias2 = b_ih[o0 + 2] + b_hh[o0 + 2], bias3 = b_ih[o0 + 3] + b_hh[o0 + 3],
          bias4 = b_ih[o0 + 4] + b_hh[o0 + 4];
    float wfc0 = W_fc[o0 + 0], wfc1 = W_fc[o0 + 1], wfc2 = W_fc[o0 + 2],
          wfc3 = W_fc[o0 + 3], wfc4 = W_fc[o0 + 4];

    float h0 = 0.0f, h1 = 0.0f, h2 = 0.0f, h3 = 0.0f, h4 = 0.0f;

    const float4* x4 = (const float4*)(x + (size_t)b * RNN_T);

#pragma unroll 1
    for (int t4 = 0; t4 < RNN_T / 4; ++t4) {
        const float4 xv = x4[t4];  // same addr across the quad (cache broadcast)
        STEP(xv.x);
        STEP(xv.y);
        STEP(xv.z);
        STEP(xv.w);
    }

    // out[b] = sigmoid(sum_o h[o]*wfc[o] + b_fc)
    float p = fmaf(h0, wfc0, 0.0f);
    p = fmaf(h1, wfc1, p);
    p = fmaf(h2, wfc2, p);
    p = fmaf(h3, wfc3, p);
    p = fmaf(h4, wfc4, p);
    p += __shfl_xor(p, 1, 64);
    p += __shfl_xor(p, 2, 64);
    if (part == 0) {
        const float z = p + b_fc[0];
        const float e = __builtin_amdgcn_exp2f(-1.4426950408889634f * z);
        out[b] = __builtin_amdgcn_rcpf(1.0f + e);
    }
}

extern "C" void kernel_launch(void* const* d_in, const int* in_sizes, int n_in,
                              void* d_out, int out_size, void* d_ws, size_t ws_size,
                              hipStream_t stream) {
    const float* x    = (const float*)d_in[0];
    const float* W_ih = (const float*)d_in[1];
    const float* W_hh = (const float*)d_in[2];
    const float* b_ih = (const float*)d_in[3];
    const float* b_hh = (const float*)d_in[4];
    const float* W_fc = (const float*)d_in[5];
    const float* b_fc = (const float*)d_in[6];
    float* out = (float*)d_out;

    const int threads = RNN_B * 4;  // 65536 = 1024 waves = 1 wave/SIMD chip-wide
    const int block   = 256;
    rnn_fwd<<<threads / block, block, 0, stream>>>(x, W_ih, W_hh, b_ih, b_hh,
                                                   W_fc, b_fc, out);
}

// Round 4
// 740.280 us; speedup vs baseline: 1.0487x; 1.0487x over previous
//
#include <hip/hip_runtime.h>

// SimpleRNN: B=16384, T=2048, I=1, H=20, O=1, fp32.
// 4 threads per batch element, each owns 5 hidden rows (h distributed across
// a quad, exchanged per step via DPP quad_perm broadcast - VALU pipe).
// 65536 threads = 1024 waves = 1 wave/SIMD chip-wide.
//
// Round-4 changes (round 3: 682 us, 800 cyc/step vs ~360 useful):
//  - q-BLOCKED broadcasts: only 5 ha live at a time, consumed immediately
//    into all 5 accs. Round-3 hoisted all 20 ha -> live set ~153 > 132 regs
//    -> allocator REMATERIALIZED mov_dpp (~100 DPP/step instead of 20).
//    sched_barrier(0) between q-blocks pins the blocked structure.
//  - x prefetched one 4-step iteration ahead (1 wave/SIMD = no TLP; a cold
//    load consumed immediately exposes ~200-900 cyc every 4 steps).

#define RNN_T 2048
#define RNN_H 20
#define RNN_B 16384
#define NT4   (RNN_T / 4)

template <int CTRL>
__device__ __forceinline__ float qb(float v) {
    // v_mov_b32_dpp quad_perm broadcast: CTRL = q * 0x55 broadcasts quad-lane q.
    return __builtin_bit_cast(
        float, __builtin_amdgcn_mov_dpp(__builtin_bit_cast(int, v), CTRL, 0xF, 0xF, true));
}

__device__ __forceinline__ float tanh_fast(float a) {
    // tanh(a) = 1 - 2/(exp2(2*log2e*a)+1); exact limits at +/-inf.
    float e = __builtin_amdgcn_exp2f(a * 2.885390081777927f);
    float r = __builtin_amdgcn_rcpf(e + 1.0f);
    return fmaf(-2.0f, r, 1.0f);
}

// Apply M(R,C) for C = 0..19
#define COLS(M, R)                                                              \
    M(R, 0) M(R, 1) M(R, 2) M(R, 3) M(R, 4) M(R, 5) M(R, 6) M(R, 7) M(R, 8)    \
    M(R, 9) M(R, 10) M(R, 11) M(R, 12) M(R, 13) M(R, 14) M(R, 15) M(R, 16)     \
    M(R, 17) M(R, 18) M(R, 19)

#define DECLW(R, C) float w##R##_##C = Wp[(R) * RNN_H + (C)];

// One q-block: broadcast 5 h values from quad-lane Q, immediately fold into
// all 5 accumulators with weight columns C0..C4 = Q*5 .. Q*5+4.
#define QBLK(CTRL, C0, C1, C2, C3, C4)                                           \
    {                                                                            \
        const float a0 = qb<CTRL>(h0), a1 = qb<CTRL>(h1), a2 = qb<CTRL>(h2),     \
                    a3 = qb<CTRL>(h3), a4 = qb<CTRL>(h4);                        \
        acc0 = fmaf(w0_##C0, a0, acc0); acc0 = fmaf(w0_##C1, a1, acc0);          \
        acc0 = fmaf(w0_##C2, a2, acc0); acc0 = fmaf(w0_##C3, a3, acc0);          \
        acc0 = fmaf(w0_##C4, a4, acc0);                                          \
        acc1 = fmaf(w1_##C0, a0, acc1); acc1 = fmaf(w1_##C1, a1, acc1);          \
        acc1 = fmaf(w1_##C2, a2, acc1); acc1 = fmaf(w1_##C3, a3, acc1);          \
        acc1 = fmaf(w1_##C4, a4, acc1);                                          \
        acc2 = fmaf(w2_##C0, a0, acc2); acc2 = fmaf(w2_##C1, a1, acc2);          \
        acc2 = fmaf(w2_##C2, a2, acc2); acc2 = fmaf(w2_##C3, a3, acc2);          \
        acc2 = fmaf(w2_##C4, a4, acc2);                                          \
        acc3 = fmaf(w3_##C0, a0, acc3); acc3 = fmaf(w3_##C1, a1, acc3);          \
        acc3 = fmaf(w3_##C2, a2, acc3); acc3 = fmaf(w3_##C3, a3, acc3);          \
        acc3 = fmaf(w3_##C4, a4, acc3);                                          \
        acc4 = fmaf(w4_##C0, a0, acc4); acc4 = fmaf(w4_##C1, a1, acc4);          \
        acc4 = fmaf(w4_##C2, a2, acc4); acc4 = fmaf(w4_##C3, a3, acc4);          \
        acc4 = fmaf(w4_##C4, a4, acc4);                                          \
    }

// One RNN step. Reads h0..h4 (previous step, all quad lanes in lockstep),
// writes h0..h4.
#define STEP(XS)                                                                 \
    do {                                                                         \
        float acc0 = fmaf(XS, wih0, bias0);                                      \
        float acc1 = fmaf(XS, wih1, bias1);                                      \
        float acc2 = fmaf(XS, wih2, bias2);                                      \
        float acc3 = fmaf(XS, wih3, bias3);                                      \
        float acc4 = fmaf(XS, wih4, bias4);                                      \
        QBLK(0x00, 0, 1, 2, 3, 4)                                                \
        __builtin_amdgcn_sched_barrier(0);                                       \
        QBLK(0x55, 5, 6, 7, 8, 9)                                                \
        __builtin_amdgcn_sched_barrier(0);                                       \
        QBLK(0xAA, 10, 11, 12, 13, 14)                                           \
        __builtin_amdgcn_sched_barrier(0);                                       \
        QBLK(0xFF, 15, 16, 17, 18, 19)                                           \
        h0 = tanh_fast(acc0);                                                    \
        h1 = tanh_fast(acc1);                                                    \
        h2 = tanh_fast(acc2);                                                    \
        h3 = tanh_fast(acc3);                                                    \
        h4 = tanh_fast(acc4);                                                    \
    } while (0)

__attribute__((amdgpu_flat_work_group_size(256, 256), amdgpu_waves_per_eu(1, 1)))
__global__ void rnn_fwd(const float* __restrict__ x,
                        const float* __restrict__ W_ih,
                        const float* __restrict__ W_hh,
                        const float* __restrict__ b_ih,
                        const float* __restrict__ b_hh,
                        const float* __restrict__ W_fc,
                        const float* __restrict__ b_fc,
                        float* __restrict__ out) {
    const int gid  = blockIdx.x * blockDim.x + threadIdx.x;
    const int b    = gid >> 2;   // batch element
    const int part = gid & 3;    // quad-lane == which 5 rows this thread owns

    const float* Wp = W_hh + part * 5 * RNN_H;
    COLS(DECLW, 0) COLS(DECLW, 1) COLS(DECLW, 2) COLS(DECLW, 3) COLS(DECLW, 4)

    const int o0 = part * 5;
    float wih0 = W_ih[o0 + 0], wih1 = W_ih[o0 + 1], wih2 = W_ih[o0 + 2],
          wih3 = W_ih[o0 + 3], wih4 = W_ih[o0 + 4];
    float bias0 = b_ih[o0 + 0] + b_hh[o0 + 0], bias1 = b_ih[o0 + 1] + b_hh[o0 + 1],
          bias2 = b_ih[o0 + 2] + b_hh[o0 + 2], bias3 = b_ih[o0 + 3] + b_hh[o0 + 3],
          bias4 = b_ih[o0 + 4] + b_hh[o0 + 4];

    float h0 = 0.0f, h1 = 0.0f, h2 = 0.0f, h3 = 0.0f, h4 = 0.0f;

    const float4* x4 = (const float4*)(x + (size_t)b * RNN_T);

    float4 xv = x4[0];  // current iteration's 4 inputs
#pragma unroll 1
    for (int t4 = 0; t4 < NT4; ++t4) {
        // Prefetch next iteration's x one full iteration (~1400 cyc) ahead.
        const int tn = (t4 + 1 < NT4) ? (t4 + 1) : t4;
        const float4 xn = x4[tn];
        STEP(xv.x);
        STEP(xv.y);
        STEP(xv.z);
        STEP(xv.w);
        xv = xn;
    }

    // out[b] = sigmoid(sum_o h[o]*wfc[o] + b_fc)
    float wfc0 = W_fc[o0 + 0], wfc1 = W_fc[o0 + 1], wfc2 = W_fc[o0 + 2],
          wfc3 = W_fc[o0 + 3], wfc4 = W_fc[o0 + 4];
    float p = fmaf(h0, wfc0, 0.0f);
    p = fmaf(h1, wfc1, p);
    p = fmaf(h2, wfc2, p);
    p = fmaf(h3, wfc3, p);
    p = fmaf(h4, wfc4, p);
    p += __shfl_xor(p, 1, 64);
    p += __shfl_xor(p, 2, 64);
    if (part == 0) {
        const float z = p + b_fc[0];
        const float e = __builtin_amdgcn_exp2f(-1.4426950408889634f * z);
        out[b] = __builtin_amdgcn_rcpf(1.0f + e);
    }
}

extern "C" void kernel_launch(void* const* d_in, const int* in_sizes, int n_in,
                              void* d_out, int out_size, void* d_ws, size_t ws_size,
                              hipStream_t stream) {
    const float* x    = (const float*)d_in[0];
    const float* W_ih = (const float*)d_in[1];
    const float* W_hh = (const float*)d_in[2];
    const float* b_ih = (const float*)d_in[3];
    const float* b_hh = (const float*)d_in[4];
    const float* W_fc = (const float*)d_in[5];
    const float* b_fc = (const float*)d_in[6];
    float* out = (float*)d_out;

    const int threads = RNN_B * 4;  // 65536 = 1024 waves = 1 wave/SIMD chip-wide
    const int block   = 256;
    rnn_fwd<<<threads / block, block, 0, stream>>>(x, W_ih, W_hh, b_ih, b_hh,
                                                   W_fc, b_fc, out);
}

// Round 5
// 619.616 us; speedup vs baseline: 1.2529x; 1.1947x over previous
//
#include <hip/hip_runtime.h>

// SimpleRNN: B=16384, T=2048, I=1, H=20, O=1, fp32.
// 4 threads per batch element, each owns 5 hidden rows (h distributed across
// a quad, exchanged per step via DPP quad_perm broadcast - VALU pipe).
// 65536 threads = 1024 waves = 1 wave/SIMD chip-wide.
//
// Round-5 change (round 4: 640 us, ~750 cyc/step, VALU-issue-bound with only
// ~190 source insts/step): pack the dot products over COLUMN PAIRS using
// v_pk_fma_f32 (VOP3P packed fp32, 2 FMA/inst - the only path to the 157 TF
// fp32 peak). acc_r is a float2 partial-sum pair; weights pair naturally in
// memory as (w_r_c, w_r_c+1); broadcast ha values land in pair slots straight
// from the DPP movs. 100 fma -> 50 pk_fma; +5 horizontal adds.

#define RNN_T 2048
#define RNN_H 20
#define RNN_B 16384
#define NT4   (RNN_T / 4)

typedef float v2f __attribute__((ext_vector_type(2)));

template <int CTRL>
__device__ __forceinline__ float qb(float v) {
    // v_mov_b32_dpp quad_perm broadcast: CTRL = q * 0x55 broadcasts quad-lane q.
    return __builtin_bit_cast(
        float, __builtin_amdgcn_mov_dpp(__builtin_bit_cast(int, v), CTRL, 0xF, 0xF, true));
}

__device__ __forceinline__ float tanh_fast(float a) {
    // tanh(a) = 1 - 2/(exp2(2*log2e*a)+1); exact limits at +/-inf.
    float e = __builtin_amdgcn_exp2f(a * 2.885390081777927f);
    float r = __builtin_amdgcn_rcpf(e + 1.0f);
    return fmaf(-2.0f, r, 1.0f);
}

// Weight pair declarations: wp{r}_{i} = (W[r][2i], W[r][2i+1]), i = 0..9
#define DECLW_ROW(R)                                                             \
    v2f wp##R##_0 = *(const v2f*)(Wp + (R) * RNN_H + 0);                         \
    v2f wp##R##_1 = *(const v2f*)(Wp + (R) * RNN_H + 2);                         \
    v2f wp##R##_2 = *(const v2f*)(Wp + (R) * RNN_H + 4);                         \
    v2f wp##R##_3 = *(const v2f*)(Wp + (R) * RNN_H + 6);                         \
    v2f wp##R##_4 = *(const v2f*)(Wp + (R) * RNN_H + 8);                         \
    v2f wp##R##_5 = *(const v2f*)(Wp + (R) * RNN_H + 10);                        \
    v2f wp##R##_6 = *(const v2f*)(Wp + (R) * RNN_H + 12);                        \
    v2f wp##R##_7 = *(const v2f*)(Wp + (R) * RNN_H + 14);                        \
    v2f wp##R##_8 = *(const v2f*)(Wp + (R) * RNN_H + 16);                        \
    v2f wp##R##_9 = *(const v2f*)(Wp + (R) * RNN_H + 18);

// One column-pair block: build ha pair (2 DPP movs), fold into all 5 acc pairs
// with one v_pk_fma_f32 each.
#define PBLK(I, CA, HA, CB, HB)                                                  \
    {                                                                            \
        v2f ha;                                                                  \
        ha.x = qb<CA>(HA);                                                       \
        ha.y = qb<CB>(HB);                                                       \
        acc0 = __builtin_elementwise_fma(wp0_##I, ha, acc0);                     \
        acc1 = __builtin_elementwise_fma(wp1_##I, ha, acc1);                     \
        acc2 = __builtin_elementwise_fma(wp2_##I, ha, acc2);                     \
        acc3 = __builtin_elementwise_fma(wp3_##I, ha, acc3);                     \
        acc4 = __builtin_elementwise_fma(wp4_##I, ha, acc4);                     \
    }

// One RNN step. Reads h0..h4 (previous step, all quad lanes in lockstep),
// writes h0..h4. Column c's source: quad-lane c/5, register h{c%5}.
#define STEP(XS)                                                                 \
    do {                                                                         \
        v2f xx;                                                                  \
        xx.x = (XS);                                                             \
        xx.y = (XS);                                                             \
        v2f acc0 = __builtin_elementwise_fma(wihP0, xx, biasP0);                 \
        v2f acc1 = __builtin_elementwise_fma(wihP1, xx, biasP1);                 \
        v2f acc2 = __builtin_elementwise_fma(wihP2, xx, biasP2);                 \
        v2f acc3 = __builtin_elementwise_fma(wihP3, xx, biasP3);                 \
        v2f acc4 = __builtin_elementwise_fma(wihP4, xx, biasP4);                 \
        PBLK(0, 0x00, h0, 0x00, h1)                                              \
        PBLK(1, 0x00, h2, 0x00, h3)                                              \
        PBLK(2, 0x00, h4, 0x55, h0)                                              \
        PBLK(3, 0x55, h1, 0x55, h2)                                              \
        PBLK(4, 0x55, h3, 0x55, h4)                                              \
        PBLK(5, 0xAA, h0, 0xAA, h1)                                              \
        PBLK(6, 0xAA, h2, 0xAA, h3)                                              \
        PBLK(7, 0xAA, h4, 0xFF, h0)                                              \
        PBLK(8, 0xFF, h1, 0xFF, h2)                                              \
        PBLK(9, 0xFF, h3, 0xFF, h4)                                              \
        h0 = tanh_fast(acc0.x + acc0.y);                                         \
        h1 = tanh_fast(acc1.x + acc1.y);                                         \
        h2 = tanh_fast(acc2.x + acc2.y);                                         \
        h3 = tanh_fast(acc3.x + acc3.y);                                         \
        h4 = tanh_fast(acc4.x + acc4.y);                                         \
    } while (0)

__attribute__((amdgpu_flat_work_group_size(256, 256), amdgpu_waves_per_eu(1, 1)))
__global__ void rnn_fwd(const float* __restrict__ x,
                        const float* __restrict__ W_ih,
                        const float* __restrict__ W_hh,
                        const float* __restrict__ b_ih,
                        const float* __restrict__ b_hh,
                        const float* __restrict__ W_fc,
                        const float* __restrict__ b_fc,
                        float* __restrict__ out) {
    const int gid  = blockIdx.x * blockDim.x + threadIdx.x;
    const int b    = gid >> 2;   // batch element
    const int part = gid & 3;    // quad-lane == which 5 rows this thread owns

    const float* Wp = W_hh + part * 5 * RNN_H;
    DECLW_ROW(0) DECLW_ROW(1) DECLW_ROW(2) DECLW_ROW(3) DECLW_ROW(4)

    const int o0 = part * 5;
    // Persistent (wih_r, 0) and (bias_r, 0) pairs: x-projection lands in the
    // lo half; hi half stays a pure column-pair partial sum.
    v2f wihP0 = {W_ih[o0 + 0], 0.0f}, wihP1 = {W_ih[o0 + 1], 0.0f},
        wihP2 = {W_ih[o0 + 2], 0.0f}, wihP3 = {W_ih[o0 + 3], 0.0f},
        wihP4 = {W_ih[o0 + 4], 0.0f};
    v2f biasP0 = {b_ih[o0 + 0] + b_hh[o0 + 0], 0.0f},
        biasP1 = {b_ih[o0 + 1] + b_hh[o0 + 1], 0.0f},
        biasP2 = {b_ih[o0 + 2] + b_hh[o0 + 2], 0.0f},
        biasP3 = {b_ih[o0 + 3] + b_hh[o0 + 3], 0.0f},
        biasP4 = {b_ih[o0 + 4] + b_hh[o0 + 4], 0.0f};

    float h0 = 0.0f, h1 = 0.0f, h2 = 0.0f, h3 = 0.0f, h4 = 0.0f;

    const float4* x4 = (const float4*)(x + (size_t)b * RNN_T);

    float4 xv = x4[0];  // current iteration's 4 inputs
#pragma unroll 1
    for (int t4 = 0; t4 < NT4; ++t4) {
        // Prefetch next iteration's x one full iteration ahead.
        const int tn = (t4 + 1 < NT4) ? (t4 + 1) : t4;
        const float4 xn = x4[tn];
        STEP(xv.x);
        STEP(xv.y);
        STEP(xv.z);
        STEP(xv.w);
        xv = xn;
    }

    // out[b] = sigmoid(sum_o h[o]*wfc[o] + b_fc)
    float wfc0 = W_fc[o0 + 0], wfc1 = W_fc[o0 + 1], wfc2 = W_fc[o0 + 2],
          wfc3 = W_fc[o0 + 3], wfc4 = W_fc[o0 + 4];
    float p = fmaf(h0, wfc0, 0.0f);
    p = fmaf(h1, wfc1, p);
    p = fmaf(h2, wfc2, p);
    p = fmaf(h3, wfc3, p);
    p = fmaf(h4, wfc4, p);
    p += __shfl_xor(p, 1, 64);
    p += __shfl_xor(p, 2, 64);
    if (part == 0) {
        const float z = p + b_fc[0];
        const float e = __builtin_amdgcn_exp2f(-1.4426950408889634f * z);
        out[b] = __builtin_amdgcn_rcpf(1.0f + e);
    }
}

extern "C" void kernel_launch(void* const* d_in, const int* in_sizes, int n_in,
                              void* d_out, int out_size, void* d_ws, size_t ws_size,
                              hipStream_t stream) {
    const float* x    = (const float*)d_in[0];
    const float* W_ih = (const float*)d_in[1];
    const float* W_hh = (const float*)d_in[2];
    const float* b_ih = (const float*)d_in[3];
    const float* b_hh = (const float*)d_in[4];
    const float* W_fc = (const float*)d_in[5];
    const float* b_fc = (const float*)d_in[6];
    float* out = (float*)d_out;

    const int threads = RNN_B * 4;  // 65536 = 1024 waves = 1 wave/SIMD chip-wide
    const int block   = 256;
    rnn_fwd<<<threads / block, block, 0, stream>>>(x, W_ih, W_hh, b_ih, b_hh,
                                                   W_fc, b_fc, out);
}